// Round 6
// baseline (764.993 us; speedup 1.0000x reference)
//
#include <hip/hip_runtime.h>
#include <math.h>

#define H_HERBS 25000
#define DIM 128
#define G_HERBS 16          // herbs per k_seg_attn block
#define SCAP 1024           // score rows per block (avg ~320, max ~400)

// ---------------- K1: segment starts via binary search (indices sorted) ---
__global__ void k_starts(const int* __restrict__ idxA, const int* __restrict__ idxB,
                         int nA, int nB, int* __restrict__ startA, int* __restrict__ startB) {
    int h = blockIdx.x * blockDim.x + threadIdx.x;
    if (h > H_HERBS) return;
    {
        int lo = 0, hi = nA;
        while (lo < hi) { int mid = (lo + hi) >> 1; if (idxA[mid] < h) lo = mid + 1; else hi = mid; }
        startA[h] = lo;
    }
    {
        int lo = 0, hi = nB;
        while (lo < hi) { int mid = (lo + hi) >> 1; if (idxB[mid] < h) lo = mid + 1; else hi = mid; }
        startB[h] = lo;
    }
}

// ---------------- K2: per-herb mean projected through aw1[128:256,:] + ab1
__global__ __launch_bounds__(64) void k_mean_both(
        const float* __restrict__ hA, const float* __restrict__ hB,
        const int* __restrict__ startA, const int* __restrict__ startB,
        const float* __restrict__ aw1, const float* __restrict__ ab1,
        float* __restrict__ mpartA, float* __restrict__ mpartB) {
    int bid = blockIdx.x;
    bool sideA = bid < H_HERBS;              // sideA -> reads B rows
    int h = sideA ? bid : bid - H_HERBS;
    const float* X = sideA ? hB : hA;
    const int* start = sideA ? startB : startA;
    float* mpart = sideA ? mpartA : mpartB;

    int lane = threadIdx.x;
    int half = lane >> 5, li = lane & 31;
    int s = start[h], e = start[h + 1];
    const float4* X4 = (const float4*)X;
    float4 acc = make_float4(0.f, 0.f, 0.f, 0.f);
    int r = s + half;
    for (; r + 6 < e; r += 8) {
        float4 v0 = X4[(size_t)r * 32 + li];
        float4 v1 = X4[(size_t)(r + 2) * 32 + li];
        float4 v2 = X4[(size_t)(r + 4) * 32 + li];
        float4 v3 = X4[(size_t)(r + 6) * 32 + li];
        acc.x += (v0.x + v1.x) + (v2.x + v3.x);
        acc.y += (v0.y + v1.y) + (v2.y + v3.y);
        acc.z += (v0.z + v1.z) + (v2.z + v3.z);
        acc.w += (v0.w + v1.w) + (v2.w + v3.w);
    }
    for (; r < e; r += 2) {
        float4 v0 = X4[(size_t)r * 32 + li];
        acc.x += v0.x; acc.y += v0.y; acc.z += v0.z; acc.w += v0.w;
    }
    acc.x += __shfl_xor(acc.x, 32, 64);
    acc.y += __shfl_xor(acc.y, 32, 64);
    acc.z += __shfl_xor(acc.z, 32, 64);
    acc.w += __shfl_xor(acc.w, 32, 64);

    int cnt = e - s;
    float inv = 1.0f / (float)(cnt > 1 ? cnt : 1);
    __shared__ float mean[DIM];
    if (half == 0) {
        mean[4 * li]     = acc.x * inv;
        mean[4 * li + 1] = acc.y * inv;
        mean[4 * li + 2] = acc.z * inv;
        mean[4 * li + 3] = acc.w * inv;
    }
    __syncthreads();
    int j = lane;
    float m = ab1[j];
    #pragma unroll 8
    for (int k = 0; k < 128; ++k) {
        m += mean[k] * aw1[(size_t)(128 + k) * 64 + j];
    }
    mpart[(size_t)h * 64 + j] = m;
}

// ---------------- K3: fused scores + softmax + weighted sum ---------------
// Block = 16 consecutive herbs (rows rs..re contiguous). Phase A: scores via
// round-5 mapping (64 grp x 4 consecutive rows per 256-row chunk, 4-way j
// split, double-buffered X). Phase B1: softmax per wave (4 herbs each).
// Phase B2: weighted sum per wave-pair (8 herbs each, thread-per-column);
// X rows are L2-resident from phase A.
__global__ __launch_bounds__(256) void k_seg_attn(
        const float* __restrict__ XA, const int* __restrict__ idxA,
        const int* __restrict__ startA, const float* __restrict__ mpartA,
        const float* __restrict__ XB, const int* __restrict__ idxB,
        const int* __restrict__ startB, const float* __restrict__ mpartB,
        const float* __restrict__ aw1, const float* __restrict__ aw2,
        const float* __restrict__ ab2, int nblk,
        float* __restrict__ outA, float* __restrict__ outB) {
    bool isA = (int)blockIdx.x < nblk;
    int blk = isA ? blockIdx.x : blockIdx.x - nblk;
    const float* X = isA ? XA : XB;
    const int* idx = isA ? idxA : idxB;
    const int* start = isA ? startA : startB;
    const float* mpart = isA ? mpartA : mpartB;
    float* out = isA ? outA : outB;

    __shared__ float4 Wl[128 * 16];   // 32 KB
    __shared__ float sc[SCAP];        // 4 KB

    int t = threadIdx.x;
    const float4* W4 = (const float4*)aw1;
    #pragma unroll
    for (int q = 0; q < 8; ++q) Wl[t + 256 * q] = W4[t + 256 * q];
    __syncthreads();

    int h0 = blk * G_HERBS;
    int hEnd = h0 + G_HERBS; if (hEnd > H_HERBS) hEnd = H_HERBS;
    int rs = start[h0];
    int re = start[hEnd];
    int cntb = re - rs; if (cntb > SCAP) cntb = SCAP;

    int grp = t >> 2, jq = t & 3;
    float4 a2r[4];
    {
        const float4* A24 = ((const float4*)aw2) + jq * 4;
        #pragma unroll
        for (int q = 0; q < 4; ++q) a2r[q] = A24[q];
    }
    float b2s = ab2[0];
    const float4* Wbase = Wl + jq * 4;

    // ---- phase A: scores (non-redundant 256-row chunks) ----
    for (int c0 = 0; c0 < cntb; c0 += 256) {
        int lr[4]; bool vm[4];
        const float4* Xp[4];
        #pragma unroll
        for (int m = 0; m < 4; ++m) {
            lr[m] = c0 + grp * 4 + m;
            vm[m] = lr[m] < cntb;
            Xp[m] = (const float4*)(X + (size_t)(rs + (vm[m] ? lr[m] : 0)) * DIM);
        }

        float4 acc[4][4];
        #pragma unroll
        for (int m = 0; m < 4; ++m)
            #pragma unroll
            for (int q = 0; q < 4; ++q) acc[m][q] = make_float4(0.f, 0.f, 0.f, 0.f);

        float4 xa[4], xb[4];
        #pragma unroll
        for (int m = 0; m < 4; ++m) xa[m] = Xp[m][0];

#define SCORE_STEP(XV, KQ)                                                   \
        {                                                                    \
            _Pragma("unroll")                                                \
            for (int kk = 0; kk < 4; ++kk) {                                 \
                int k = (KQ) * 4 + kk;                                       \
                float4 w[4];                                                 \
                _Pragma("unroll")                                            \
                for (int q = 0; q < 4; ++q) w[q] = Wbase[k * 16 + q];        \
                _Pragma("unroll")                                            \
                for (int m = 0; m < 4; ++m) {                                \
                    float x = (&XV[m].x)[kk];                                \
                    _Pragma("unroll")                                        \
                    for (int q = 0; q < 4; ++q) {                            \
                        acc[m][q].x += x * w[q].x; acc[m][q].y += x * w[q].y;\
                        acc[m][q].z += x * w[q].z; acc[m][q].w += x * w[q].w;\
                    }                                                        \
                }                                                            \
            }                                                                \
        }

        for (int kq = 0; kq < 32; kq += 2) {
            #pragma unroll
            for (int m = 0; m < 4; ++m) xb[m] = Xp[m][kq + 1];
            SCORE_STEP(xa, kq)
            if (kq + 2 < 32) {
                #pragma unroll
                for (int m = 0; m < 4; ++m) xa[m] = Xp[m][kq + 2];
            }
            SCORE_STEP(xb, kq + 1)
        }
#undef SCORE_STEP

        #pragma unroll
        for (int m = 0; m < 4; ++m) {
            int h = vm[m] ? idx[rs + lr[m]] : 0;
            const float4* mp = (const float4*)(mpart + (size_t)h * 64) + jq * 4;
            float s = 0.f;
            #pragma unroll
            for (int q = 0; q < 4; ++q) {
                float4 mv = mp[q];
                float hx = acc[m][q].x + mv.x, hy = acc[m][q].y + mv.y;
                float hz = acc[m][q].z + mv.z, hw = acc[m][q].w + mv.w;
                hx = hx > 0.f ? hx : 0.2f * hx; hy = hy > 0.f ? hy : 0.2f * hy;
                hz = hz > 0.f ? hz : 0.2f * hz; hw = hw > 0.f ? hw : 0.2f * hw;
                s += hx * a2r[q].x + hy * a2r[q].y + hz * a2r[q].z + hw * a2r[q].w;
            }
            s += __shfl_xor(s, 1, 64);
            s += __shfl_xor(s, 2, 64);
            if (jq == 0 && vm[m]) sc[lr[m]] = s + b2s;
        }
    }
    __syncthreads();

    // ---- phase B1: softmax, wave w handles herbs w, w+4, w+8, w+12 ----
    {
        int wv = t >> 6, ln = t & 63;
        for (int i = 0; i < 4; ++i) {
            int h = h0 + wv + 4 * i;
            if (h >= H_HERBS) continue;
            int ls = start[h] - rs, le = start[h + 1] - rs;
            if (ls > cntb) ls = cntb;
            if (le > cntb) le = cntb;
            if (le <= ls) continue;
            float mx = -INFINITY;
            for (int r = ls + ln; r < le; r += 64) mx = fmaxf(mx, sc[r]);
            #pragma unroll
            for (int o = 32; o; o >>= 1) mx = fmaxf(mx, __shfl_xor(mx, o, 64));
            float sum = 0.f;
            for (int r = ls + ln; r < le; r += 64) {
                float e = __expf(sc[r] - mx);
                sc[r] = e;
                sum += e;
            }
            #pragma unroll
            for (int o = 32; o; o >>= 1) sum += __shfl_xor(sum, o, 64);
            float invden = 1.0f / (sum + 1e-16f);
            for (int r = ls + ln; r < le; r += 64) sc[r] *= invden;
        }
    }
    __syncthreads();

    // ---- phase B2: weighted sum, wave-pair wp handles 8 herbs ----
    {
        int wp = t >> 7, c = t & 127;
        for (int q = 0; q < 8; ++q) {
            int h = h0 + wp * 8 + q;
            if (h >= H_HERBS) break;
            int ls = start[h] - rs, le = start[h + 1] - rs;
            if (ls > cntb) ls = cntb;
            if (le > cntb) le = cntb;
            float O = 0.f;
            int r = ls;
            for (; r + 4 <= le; r += 4) {
                float x0 = X[(size_t)(rs + r)     * DIM + c];
                float x1 = X[(size_t)(rs + r + 1) * DIM + c];
                float x2 = X[(size_t)(rs + r + 2) * DIM + c];
                float x3 = X[(size_t)(rs + r + 3) * DIM + c];
                O += sc[r] * x0 + sc[r + 1] * x1 + sc[r + 2] * x2 + sc[r + 3] * x3;
            }
            for (; r < le; ++r) O += sc[r] * X[(size_t)(rs + r) * DIM + c];
            out[(size_t)h * DIM + c] = O;
        }
    }
}

// ---------------- K4: fusion MLP, register-tiled GEMM -----------------
#define HPB 16
__global__ __launch_bounds__(256) void k_fusion(
        const float* __restrict__ HA, const float* __restrict__ HB,
        const float* __restrict__ fw1, const float* __restrict__ fb1,
        const float* __restrict__ fw2, const float* __restrict__ fb2,
        float* __restrict__ out) {
    __shared__ float feat[HPB][512];
    __shared__ float hid[HPB][256];
    int t = threadIdx.x;
    int h0 = blockIdx.x * HPB;

    for (int idx = t; idx < HPB * DIM; idx += 256) {
        int hh = idx >> 7, c = idx & 127;
        int h = h0 + hh;
        float a = 0.f, b = 0.f;
        if (h < H_HERBS) { a = HA[(size_t)h * DIM + c]; b = HB[(size_t)h * DIM + c]; }
        feat[hh][c]       = a;
        feat[hh][128 + c] = b;
        feat[hh][256 + c] = a * b;
        feat[hh][384 + c] = fabsf(a - b);
    }
    __syncthreads();

    {
        int c = t & 63, g = t >> 6;
        float4 acc[4];
        #pragma unroll
        for (int m = 0; m < 4; ++m) acc[m] = make_float4(0.f, 0.f, 0.f, 0.f);
        const float4* W1 = (const float4*)fw1;
        for (int k = 0; k < 512; k += 4) {
            float4 w0 = W1[(size_t)(k + 0) * 64 + c];
            float4 w1 = W1[(size_t)(k + 1) * 64 + c];
            float4 w2 = W1[(size_t)(k + 2) * 64 + c];
            float4 w3 = W1[(size_t)(k + 3) * 64 + c];
            #pragma unroll
            for (int m = 0; m < 4; ++m) {
                float4 f = *(const float4*)&feat[4 * g + m][k];
                acc[m].x += f.x * w0.x + f.y * w1.x + f.z * w2.x + f.w * w3.x;
                acc[m].y += f.x * w0.y + f.y * w1.y + f.z * w2.y + f.w * w3.y;
                acc[m].z += f.x * w0.z + f.y * w1.z + f.z * w2.z + f.w * w3.z;
                acc[m].w += f.x * w0.w + f.y * w1.w + f.z * w2.w + f.w * w3.w;
            }
        }
        float4 b1v = ((const float4*)fb1)[c];
        #pragma unroll
        for (int m = 0; m < 4; ++m) {
            float4 hv;
            hv.x = fmaxf(acc[m].x + b1v.x, 0.f);
            hv.y = fmaxf(acc[m].y + b1v.y, 0.f);
            hv.z = fmaxf(acc[m].z + b1v.z, 0.f);
            hv.w = fmaxf(acc[m].w + b1v.w, 0.f);
            *(float4*)&hid[4 * g + m][4 * c] = hv;
        }
    }
    __syncthreads();

    {
        int c2 = t & 31, g2 = t >> 5;
        float4 acc[2];
        #pragma unroll
        for (int m = 0; m < 2; ++m) acc[m] = make_float4(0.f, 0.f, 0.f, 0.f);
        const float4* W2 = (const float4*)fw2;
        for (int k = 0; k < 256; k += 4) {
            float4 w0 = W2[(size_t)(k + 0) * 32 + c2];
            float4 w1 = W2[(size_t)(k + 1) * 32 + c2];
            float4 w2v = W2[(size_t)(k + 2) * 32 + c2];
            float4 w3 = W2[(size_t)(k + 3) * 32 + c2];
            #pragma unroll
            for (int m = 0; m < 2; ++m) {
                float4 hv = *(const float4*)&hid[2 * g2 + m][k];
                acc[m].x += hv.x * w0.x + hv.y * w1.x + hv.z * w2v.x + hv.w * w3.x;
                acc[m].y += hv.x * w0.y + hv.y * w1.y + hv.z * w2v.y + hv.w * w3.y;
                acc[m].z += hv.x * w0.z + hv.y * w1.z + hv.z * w2v.z + hv.w * w3.z;
                acc[m].w += hv.x * w0.w + hv.y * w1.w + hv.z * w2v.w + hv.w * w3.w;
            }
        }
        float4 b2v = ((const float4*)fb2)[c2];
        #pragma unroll
        for (int m = 0; m < 2; ++m) {
            int h = h0 + 2 * g2 + m;
            if (h < H_HERBS) {
                float4 o;
                o.x = acc[m].x + b2v.x; o.y = acc[m].y + b2v.y;
                o.z = acc[m].z + b2v.z; o.w = acc[m].w + b2v.w;
                ((float4*)out)[(size_t)h * 32 + c2] = o;
            }
        }
    }
}

extern "C" void kernel_launch(void* const* d_in, const int* in_sizes, int n_in,
                              void* d_out, int out_size, void* d_ws, size_t ws_size,
                              hipStream_t stream) {
    const float* hA  = (const float*)d_in[0];
    const float* hB  = (const float*)d_in[1];
    const int*   idxA = (const int*)d_in[2];
    const int*   idxB = (const int*)d_in[3];
    const float* aw1 = (const float*)d_in[5];
    const float* ab1 = (const float*)d_in[6];
    const float* aw2 = (const float*)d_in[7];
    const float* ab2 = (const float*)d_in[8];
    const float* fw1 = (const float*)d_in[9];
    const float* fb1 = (const float*)d_in[10];
    const float* fw2 = (const float*)d_in[11];
    const float* fb2 = (const float*)d_in[12];

    int nA = in_sizes[0] / DIM;
    int nB = in_sizes[1] / DIM;

    float* out  = (float*)d_out;
    float* outI = out;
    float* outA = out + (size_t)H_HERBS * DIM;
    float* outB = out + (size_t)2 * H_HERBS * DIM;

    char* w = (char*)d_ws;
    auto carve = [&](size_t bytes) { char* p = w; w += (bytes + 255) & ~(size_t)255; return p; };
    int*   startA  = (int*)carve((size_t)(H_HERBS + 1) * sizeof(int));
    int*   startB  = (int*)carve((size_t)(H_HERBS + 1) * sizeof(int));
    float* mpartA  = (float*)carve((size_t)H_HERBS * 64 * sizeof(float));
    float* mpartB  = (float*)carve((size_t)H_HERBS * 64 * sizeof(float));

    k_starts<<<(H_HERBS + 1 + 255) / 256, 256, 0, stream>>>(idxA, idxB, nA, nB, startA, startB);

    k_mean_both<<<2 * H_HERBS, 64, 0, stream>>>(hA, hB, startA, startB, aw1, ab1, mpartA, mpartB);

    int nblk = (H_HERBS + G_HERBS - 1) / G_HERBS;
    k_seg_attn<<<2 * nblk, 256, 0, stream>>>(hA, idxA, startA, mpartA,
                                             hB, idxB, startB, mpartB,
                                             aw1, aw2, ab2, nblk, outA, outB);

    k_fusion<<<(H_HERBS + HPB - 1) / HPB, 256, 0, stream>>>(outA, outB, fw1, fb1, fw2, fb2, outI);
}

// Round 7
// 720.816 us; speedup vs baseline: 1.0613x; 1.0613x over previous
//
#include <hip/hip_runtime.h>
#include <math.h>

#define H_HERBS 25000
#define DIM 128
#define G 16            // herbs per block
#define SCAP 640        // score rows per block (avg ~320, 18 sigma margin)

// ---------------- K1: segment starts via binary search (indices sorted) ---
__global__ void k_starts(const int* __restrict__ idxA, const int* __restrict__ idxB,
                         int nA, int nB, int* __restrict__ startA, int* __restrict__ startB) {
    int h = blockIdx.x * blockDim.x + threadIdx.x;
    if (h > H_HERBS) return;
    {
        int lo = 0, hi = nA;
        while (lo < hi) { int mid = (lo + hi) >> 1; if (idxA[mid] < h) lo = mid + 1; else hi = mid; }
        startA[h] = lo;
    }
    {
        int lo = 0, hi = nB;
        while (lo < hi) { int mid = (lo + hi) >> 1; if (idxB[mid] < h) lo = mid + 1; else hi = mid; }
        startB[h] = lo;
    }
}

// ---------------- K2: mega kernel — block = 16 herbs, both sides + fusion --
// Sequence: meanB -> mpartA -> scoresA -> softmaxA -> weightedA(+meanA)
//        -> mpartB -> scoresB -> softmaxB -> weightedB -> fusion MLP.
// LDS union: [Wl 32K | sc 2.5K | meanbuf 8K | mpartl 4K] then [feat 32K | hid 16K].
__global__ __launch_bounds__(256) void k_mega(
        const float* __restrict__ XA, const int* __restrict__ idxA,
        const int* __restrict__ startA,
        const float* __restrict__ XB, const int* __restrict__ idxB,
        const int* __restrict__ startB,
        const float* __restrict__ aw1, const float* __restrict__ ab1,
        const float* __restrict__ aw2, const float* __restrict__ ab2,
        const float* __restrict__ fw1, const float* __restrict__ fb1,
        const float* __restrict__ fw2, const float* __restrict__ fb2,
        float* __restrict__ outI, float* __restrict__ outA, float* __restrict__ outB) {
    __shared__ __align__(16) char smem[49152];
    float4* Wl      = (float4*)smem;                  // aw1[0:128,:]  32768 B
    float*  sc      = (float*)(smem + 32768);         // scores        2560 B
    float*  meanbuf = (float*)(smem + 35328);         // [16][128]     8192 B
    float*  mpartl  = (float*)(smem + 43520);         // [16][64]      4096 B

    const int t = threadIdx.x;
    const int h0 = blockIdx.x * G;
    int nh = H_HERBS - h0; if (nh > G) nh = G;

    // stage W1a (x-part) into LDS
    {
        const float4* W4 = (const float4*)aw1;
        #pragma unroll
        for (int q = 0; q < 8; ++q) Wl[t + 256 * q] = W4[t + 256 * q];
    }

    const int wv = t >> 6, ln = t & 63, half = ln >> 5, li = ln & 31;

    // ---- M1: mean of B segments -> meanbuf ----
    for (int hh = wv; hh < nh; hh += 4) {
        int h = h0 + hh;
        int s = startB[h], e = startB[h + 1];
        const float4* X4 = (const float4*)XB;
        float4 acc = make_float4(0.f, 0.f, 0.f, 0.f);
        int r = s + half;
        for (; r + 2 < e; r += 4) {
            float4 v0 = X4[(size_t)r * 32 + li];
            float4 v1 = X4[(size_t)(r + 2) * 32 + li];
            acc.x += v0.x + v1.x; acc.y += v0.y + v1.y;
            acc.z += v0.z + v1.z; acc.w += v0.w + v1.w;
        }
        if (r < e) {
            float4 v0 = X4[(size_t)r * 32 + li];
            acc.x += v0.x; acc.y += v0.y; acc.z += v0.z; acc.w += v0.w;
        }
        acc.x += __shfl_xor(acc.x, 32, 64);
        acc.y += __shfl_xor(acc.y, 32, 64);
        acc.z += __shfl_xor(acc.z, 32, 64);
        acc.w += __shfl_xor(acc.w, 32, 64);
        int cntm = e - s;
        float inv = 1.0f / (float)(cntm > 1 ? cntm : 1);
        if (half == 0) {
            float4 mv = make_float4(acc.x * inv, acc.y * inv, acc.z * inv, acc.w * inv);
            ((float4*)(meanbuf + hh * 128))[li] = mv;
        }
    }
    __syncthreads();

    // ---- two sides: side 0 = A (weighted phase also fills meanbuf with meanA) ----
    for (int side = 0; side < 2; ++side) {
        const float* X = side ? XB : XA;
        const int* idx = side ? idxB : idxA;
        const int* start = side ? startB : startA;
        float* outX = side ? outB : outA;

        // ---- P: mpartl[hh][j] = ab1[j] + dot(meanbuf[hh], aw1[128:,j]) ----
        {
            int j = t & 63, hb4 = (t >> 6) * 4;
            float ab1j = ab1[j];
            float mreg[4];
            #pragma unroll
            for (int i = 0; i < 4; ++i) mreg[i] = ab1j;
            for (int k = 0; k < 128; ++k) {
                float w = aw1[(size_t)(128 + k) * 64 + j];
                #pragma unroll
                for (int i = 0; i < 4; ++i)
                    mreg[i] += meanbuf[(hb4 + i) * 128 + k] * w;
            }
            #pragma unroll
            for (int i = 0; i < 4; ++i)
                if (hb4 + i < nh) mpartl[(hb4 + i) * 64 + j] = mreg[i];
        }
        __syncthreads();

        int rs = start[h0];
        int re = start[h0 + nh];
        int cnt = re - rs; if (cnt > SCAP) cnt = SCAP;

        // ---- S: scores (non-redundant rows, wave-coherent skip) ----
        {
            int grp = t >> 2, jq = t & 3;
            float4 a2r[4];
            {
                const float4* A24 = ((const float4*)aw2) + jq * 4;
                #pragma unroll
                for (int q = 0; q < 4; ++q) a2r[q] = A24[q];
            }
            float b2s = ab2[0];
            const float4* Wbase = Wl + jq * 4;

            for (int c0 = 0; c0 < cnt; c0 += 256) {
                int r0 = c0 + grp * 4;
                if (r0 >= cnt) continue;     // wave-coherent skip (64-row granularity)
                int lr[4]; bool vm[4];
                const float4* Xp[4];
                #pragma unroll
                for (int m = 0; m < 4; ++m) {
                    lr[m] = r0 + m;
                    vm[m] = lr[m] < cnt;
                    Xp[m] = (const float4*)(X + (size_t)(rs + (vm[m] ? lr[m] : r0)) * DIM);
                }

                float4 acc[4][4];
                #pragma unroll
                for (int m = 0; m < 4; ++m)
                    #pragma unroll
                    for (int q = 0; q < 4; ++q) acc[m][q] = make_float4(0.f, 0.f, 0.f, 0.f);

                float4 xa[4], xb[4];
                #pragma unroll
                for (int m = 0; m < 4; ++m) xa[m] = Xp[m][0];

#define SCORE_STEP(XV, KQ)                                                   \
                {                                                            \
                    _Pragma("unroll")                                        \
                    for (int kk = 0; kk < 4; ++kk) {                         \
                        int k = (KQ) * 4 + kk;                               \
                        float4 w[4];                                         \
                        _Pragma("unroll")                                    \
                        for (int q = 0; q < 4; ++q) w[q] = Wbase[k * 16 + q];\
                        _Pragma("unroll")                                    \
                        for (int m = 0; m < 4; ++m) {                        \
                            float x = (&XV[m].x)[kk];                        \
                            _Pragma("unroll")                                \
                            for (int q = 0; q < 4; ++q) {                    \
                                acc[m][q].x += x * w[q].x;                   \
                                acc[m][q].y += x * w[q].y;                   \
                                acc[m][q].z += x * w[q].z;                   \
                                acc[m][q].w += x * w[q].w;                   \
                            }                                                \
                        }                                                    \
                    }                                                        \
                }

                for (int kq = 0; kq < 32; kq += 2) {
                    #pragma unroll
                    for (int m = 0; m < 4; ++m) xb[m] = Xp[m][kq + 1];
                    SCORE_STEP(xa, kq)
                    if (kq + 2 < 32) {
                        #pragma unroll
                        for (int m = 0; m < 4; ++m) xa[m] = Xp[m][kq + 2];
                    }
                    SCORE_STEP(xb, kq + 1)
                }
#undef SCORE_STEP

                #pragma unroll
                for (int m = 0; m < 4; ++m) {
                    int hidx = vm[m] ? (idx[rs + lr[m]] - h0) : 0;
                    const float4* mp = (const float4*)(mpartl + hidx * 64) + jq * 4;
                    float s = 0.f;
                    #pragma unroll
                    for (int q = 0; q < 4; ++q) {
                        float4 mv = mp[q];
                        float hx = acc[m][q].x + mv.x, hy = acc[m][q].y + mv.y;
                        float hz = acc[m][q].z + mv.z, hw = acc[m][q].w + mv.w;
                        hx = hx > 0.f ? hx : 0.2f * hx; hy = hy > 0.f ? hy : 0.2f * hy;
                        hz = hz > 0.f ? hz : 0.2f * hz; hw = hw > 0.f ? hw : 0.2f * hw;
                        s += hx * a2r[q].x + hy * a2r[q].y + hz * a2r[q].z + hw * a2r[q].w;
                    }
                    s += __shfl_xor(s, 1, 64);
                    s += __shfl_xor(s, 2, 64);
                    if (jq == 0 && vm[m]) sc[lr[m]] = s + b2s;
                }
            }
        }
        __syncthreads();

        // ---- SM: per-herb softmax in sc (wave wv: herbs wv, wv+4, ...) ----
        for (int i = wv; i < nh; i += 4) {
            int h = h0 + i;
            int ls = start[h] - rs, le = start[h + 1] - rs;
            if (ls > cnt) ls = cnt;
            if (le > cnt) le = cnt;
            if (le <= ls) continue;
            float mx = -INFINITY;
            for (int r = ls + ln; r < le; r += 64) mx = fmaxf(mx, sc[r]);
            #pragma unroll
            for (int o = 32; o; o >>= 1) mx = fmaxf(mx, __shfl_xor(mx, o, 64));
            float sum = 0.f;
            for (int r = ls + ln; r < le; r += 64) {
                float e = __expf(sc[r] - mx);
                sc[r] = e;
                sum += e;
            }
            #pragma unroll
            for (int o = 32; o; o >>= 1) sum += __shfl_xor(sum, o, 64);
            float invden = 1.0f / (sum + 1e-16f);
            for (int r = ls + ln; r < le; r += 64) sc[r] *= invden;
        }
        __syncthreads();

        // ---- W: weighted sum -> outX; also accumulate plain mean -> meanbuf ----
        {
            int wp = t >> 7, c = t & 127;
            for (int qq = 0; qq < 8; ++qq) {
                int hh = wp * 8 + qq;
                if (hh >= nh) break;
                int h = h0 + hh;
                int ls = start[h] - rs, le = start[h + 1] - rs;
                if (ls > cnt) ls = cnt;
                if (le > cnt) le = cnt;
                float O = 0.f, S = 0.f;
                int r = ls;
                for (; r + 4 <= le; r += 4) {
                    float x0 = X[(size_t)(rs + r)     * DIM + c];
                    float x1 = X[(size_t)(rs + r + 1) * DIM + c];
                    float x2 = X[(size_t)(rs + r + 2) * DIM + c];
                    float x3 = X[(size_t)(rs + r + 3) * DIM + c];
                    O += sc[r] * x0 + sc[r + 1] * x1 + sc[r + 2] * x2 + sc[r + 3] * x3;
                    S += (x0 + x1) + (x2 + x3);
                }
                for (; r < le; ++r) {
                    float x = X[(size_t)(rs + r) * DIM + c];
                    O += sc[r] * x; S += x;
                }
                outX[(size_t)h * DIM + c] = O;
                int cm = le - ls;
                meanbuf[hh * 128 + c] = S / (float)(cm > 1 ? cm : 1);
            }
        }
        __syncthreads();
    }

    // ---- fusion MLP: feat/hid reuse the LDS (all prior regions dead) ----
    float* feat = (float*)smem;            // [16][512]
    float* hid  = (float*)(smem + 32768);  // [16][256]
    for (int id = t; id < G * DIM; id += 256) {
        int hh = id >> 7, c = id & 127;
        float a = 0.f, b = 0.f;
        if (hh < nh) {
            int h = h0 + hh;
            a = outA[(size_t)h * DIM + c];
            b = outB[(size_t)h * DIM + c];
        }
        feat[hh * 512 + c]       = a;
        feat[hh * 512 + 128 + c] = b;
        feat[hh * 512 + 256 + c] = a * b;
        feat[hh * 512 + 384 + c] = fabsf(a - b);
    }
    __syncthreads();

    {
        int c = t & 63, g = t >> 6;
        float4 acc4[4];
        #pragma unroll
        for (int m = 0; m < 4; ++m) acc4[m] = make_float4(0.f, 0.f, 0.f, 0.f);
        const float4* W1 = (const float4*)fw1;
        for (int k = 0; k < 512; k += 4) {
            float4 w0 = W1[(size_t)(k + 0) * 64 + c];
            float4 w1 = W1[(size_t)(k + 1) * 64 + c];
            float4 w2 = W1[(size_t)(k + 2) * 64 + c];
            float4 w3 = W1[(size_t)(k + 3) * 64 + c];
            #pragma unroll
            for (int m = 0; m < 4; ++m) {
                float4 f = *(const float4*)(feat + (4 * g + m) * 512 + k);
                acc4[m].x += f.x * w0.x + f.y * w1.x + f.z * w2.x + f.w * w3.x;
                acc4[m].y += f.x * w0.y + f.y * w1.y + f.z * w2.y + f.w * w3.y;
                acc4[m].z += f.x * w0.z + f.y * w1.z + f.z * w2.z + f.w * w3.z;
                acc4[m].w += f.x * w0.w + f.y * w1.w + f.z * w2.w + f.w * w3.w;
            }
        }
        float4 b1v = ((const float4*)fb1)[c];
        #pragma unroll
        for (int m = 0; m < 4; ++m) {
            float4 hv;
            hv.x = fmaxf(acc4[m].x + b1v.x, 0.f);
            hv.y = fmaxf(acc4[m].y + b1v.y, 0.f);
            hv.z = fmaxf(acc4[m].z + b1v.z, 0.f);
            hv.w = fmaxf(acc4[m].w + b1v.w, 0.f);
            *(float4*)(hid + (4 * g + m) * 256 + 4 * c) = hv;
        }
    }
    __syncthreads();

    {
        int c2 = t & 31, g2 = t >> 5;
        float4 acc2[2];
        #pragma unroll
        for (int m = 0; m < 2; ++m) acc2[m] = make_float4(0.f, 0.f, 0.f, 0.f);
        const float4* W2 = (const float4*)fw2;
        for (int k = 0; k < 256; k += 4) {
            float4 w0  = W2[(size_t)(k + 0) * 32 + c2];
            float4 w1  = W2[(size_t)(k + 1) * 32 + c2];
            float4 w2v = W2[(size_t)(k + 2) * 32 + c2];
            float4 w3  = W2[(size_t)(k + 3) * 32 + c2];
            #pragma unroll
            for (int m = 0; m < 2; ++m) {
                float4 hv = *(const float4*)(hid + (2 * g2 + m) * 256 + k);
                acc2[m].x += hv.x * w0.x + hv.y * w1.x + hv.z * w2v.x + hv.w * w3.x;
                acc2[m].y += hv.x * w0.y + hv.y * w1.y + hv.z * w2v.y + hv.w * w3.y;
                acc2[m].z += hv.x * w0.z + hv.y * w1.z + hv.z * w2v.z + hv.w * w3.z;
                acc2[m].w += hv.x * w0.w + hv.y * w1.w + hv.z * w2v.w + hv.w * w3.w;
            }
        }
        float4 b2v = ((const float4*)fb2)[c2];
        #pragma unroll
        for (int m = 0; m < 2; ++m) {
            int hh = 2 * g2 + m;
            if (hh < nh) {
                int h = h0 + hh;
                float4 o;
                o.x = acc2[m].x + b2v.x; o.y = acc2[m].y + b2v.y;
                o.z = acc2[m].z + b2v.z; o.w = acc2[m].w + b2v.w;
                ((float4*)outI)[(size_t)h * 32 + c2] = o;
            }
        }
    }
}

extern "C" void kernel_launch(void* const* d_in, const int* in_sizes, int n_in,
                              void* d_out, int out_size, void* d_ws, size_t ws_size,
                              hipStream_t stream) {
    const float* hA  = (const float*)d_in[0];
    const float* hB  = (const float*)d_in[1];
    const int*   idxA = (const int*)d_in[2];
    const int*   idxB = (const int*)d_in[3];
    const float* aw1 = (const float*)d_in[5];
    const float* ab1 = (const float*)d_in[6];
    const float* aw2 = (const float*)d_in[7];
    const float* ab2 = (const float*)d_in[8];
    const float* fw1 = (const float*)d_in[9];
    const float* fb1 = (const float*)d_in[10];
    const float* fw2 = (const float*)d_in[11];
    const float* fb2 = (const float*)d_in[12];

    int nA = in_sizes[0] / DIM;
    int nB = in_sizes[1] / DIM;

    float* out  = (float*)d_out;
    float* outI = out;
    float* outA = out + (size_t)H_HERBS * DIM;
    float* outB = out + (size_t)2 * H_HERBS * DIM;

    char* w = (char*)d_ws;
    auto carve = [&](size_t bytes) { char* p = w; w += (bytes + 255) & ~(size_t)255; return p; };
    int* startA = (int*)carve((size_t)(H_HERBS + 1) * sizeof(int));
    int* startB = (int*)carve((size_t)(H_HERBS + 1) * sizeof(int));

    k_starts<<<(H_HERBS + 1 + 255) / 256, 256, 0, stream>>>(idxA, idxB, nA, nB, startA, startB);

    int nblk = (H_HERBS + G - 1) / G;
    k_mega<<<nblk, 256, 0, stream>>>(hA, idxA, startA, hB, idxB, startB,
                                     aw1, ab1, aw2, ab2,
                                     fw1, fb1, fw2, fb2,
                                     outI, outA, outB);
}

// Round 8
// 541.499 us; speedup vs baseline: 1.4127x; 1.3312x over previous
//
#include <hip/hip_runtime.h>
#include <math.h>

#define H_HERBS 25000
#define DIM 128

typedef __attribute__((ext_vector_type(8))) short bf16x8;
typedef __attribute__((ext_vector_type(4))) float f32x4;

__device__ inline unsigned pack2bf(float a, float b) {
    union { float f; unsigned u; } x, y; x.f = a; y.f = b;
    return ((x.u + 0x8000u) >> 16) | ((y.u + 0x8000u) & 0xFFFF0000u);
}

// ---------------- K1: segment starts via binary search (indices sorted) ---
__global__ void k_starts(const int* __restrict__ idxA, const int* __restrict__ idxB,
                         int nA, int nB, int* __restrict__ startA, int* __restrict__ startB) {
    int h = blockIdx.x * blockDim.x + threadIdx.x;
    if (h > H_HERBS) return;
    {
        int lo = 0, hi = nA;
        while (lo < hi) { int mid = (lo + hi) >> 1; if (idxA[mid] < h) lo = mid + 1; else hi = mid; }
        startA[h] = lo;
    }
    {
        int lo = 0, hi = nB;
        while (lo < hi) { int mid = (lo + hi) >> 1; if (idxB[mid] < h) lo = mid + 1; else hi = mid; }
        startB[h] = lo;
    }
}

// ---------------- K2: per-herb mean projected through aw1[128:256,:] + ab1
__global__ __launch_bounds__(64) void k_mean_both(
        const float* __restrict__ hA, const float* __restrict__ hB,
        const int* __restrict__ startA, const int* __restrict__ startB,
        const float* __restrict__ aw1, const float* __restrict__ ab1,
        float* __restrict__ mpartA, float* __restrict__ mpartB) {
    int bid = blockIdx.x;
    bool sideA = bid < H_HERBS;              // sideA -> reads B rows
    int h = sideA ? bid : bid - H_HERBS;
    const float* X = sideA ? hB : hA;
    const int* start = sideA ? startB : startA;
    float* mpart = sideA ? mpartA : mpartB;

    int lane = threadIdx.x;
    int half = lane >> 5, li = lane & 31;
    int s = start[h], e = start[h + 1];
    const float4* X4 = (const float4*)X;
    float4 acc = make_float4(0.f, 0.f, 0.f, 0.f);
    int r = s + half;
    for (; r + 6 < e; r += 8) {
        float4 v0 = X4[(size_t)r * 32 + li];
        float4 v1 = X4[(size_t)(r + 2) * 32 + li];
        float4 v2 = X4[(size_t)(r + 4) * 32 + li];
        float4 v3 = X4[(size_t)(r + 6) * 32 + li];
        acc.x += (v0.x + v1.x) + (v2.x + v3.x);
        acc.y += (v0.y + v1.y) + (v2.y + v3.y);
        acc.z += (v0.z + v1.z) + (v2.z + v3.z);
        acc.w += (v0.w + v1.w) + (v2.w + v3.w);
    }
    for (; r < e; r += 2) {
        float4 v0 = X4[(size_t)r * 32 + li];
        acc.x += v0.x; acc.y += v0.y; acc.z += v0.z; acc.w += v0.w;
    }
    acc.x += __shfl_xor(acc.x, 32, 64);
    acc.y += __shfl_xor(acc.y, 32, 64);
    acc.z += __shfl_xor(acc.z, 32, 64);
    acc.w += __shfl_xor(acc.w, 32, 64);

    int cnt = e - s;
    float inv = 1.0f / (float)(cnt > 1 ? cnt : 1);
    __shared__ float mean[DIM];
    if (half == 0) {
        mean[4 * li]     = acc.x * inv;
        mean[4 * li + 1] = acc.y * inv;
        mean[4 * li + 2] = acc.z * inv;
        mean[4 * li + 3] = acc.w * inv;
    }
    __syncthreads();
    int j = lane;
    float m = ab1[j];
    #pragma unroll 8
    for (int k = 0; k < 128; ++k) {
        m += mean[k] * aw1[(size_t)(128 + k) * 64 + j];
    }
    mpart[(size_t)h * 64 + j] = m;
}

// ---------------- K3: attention scores via MFMA (bf16 in, f32 acc) --------
// Block = 256 rows (4 waves x 4 passes x 16-row M-tile). W1a held as MFMA
// B-fragments in registers (loaded once); X rows loaded per-lane directly
// in A-fragment layout and packed to bf16. Epilogue: + mpart, leakyrelu,
// dot aw2, 16-lane shfl reduce.
// Layouts (gfx950 16x16x32 bf16): A: row=lane&15, k=(lane>>4)*8+e;
// B: col=lane&15, k=(lane>>4)*8+e; C/D: col=lane&15, row=(lane>>4)*4+reg.
__global__ __launch_bounds__(256) void k_scores_mfma(
        const float* __restrict__ XA, const int* __restrict__ idxA,
        const float* __restrict__ mpartA, int nA, int gridA,
        const float* __restrict__ XB, const int* __restrict__ idxB,
        const float* __restrict__ mpartB, int nB,
        const float* __restrict__ aw1, const float* __restrict__ aw2,
        const float* __restrict__ ab2,
        float* __restrict__ scoresA, float* __restrict__ scoresB) {
    bool isA = (int)blockIdx.x < gridA;
    int blk = isA ? blockIdx.x : blockIdx.x - gridA;
    const float* X = isA ? XA : XB;
    const int* idx = isA ? idxA : idxB;
    const float* mpart = isA ? mpartA : mpartB;
    float* scores = isA ? scoresA : scoresB;
    int n = isA ? nA : nB;

    int t = threadIdx.x;
    int l = t & 63, wid = t >> 6;
    int c = l & 15, kg = l >> 4;

    union ABu { bf16x8 v; unsigned u[4]; };

    // preload W fragments: wf[kb][nb], k = kb*32 + kg*8 + e, j = nb*16 + c
    ABu wf[4][4];
    #pragma unroll
    for (int kb = 0; kb < 4; ++kb) {
        int k0 = kb * 32 + kg * 8;
        #pragma unroll
        for (int nb = 0; nb < 4; ++nb) {
            int j = nb * 16 + c;
            #pragma unroll
            for (int e = 0; e < 4; ++e) {
                wf[kb][nb].u[e] = pack2bf(aw1[(size_t)(k0 + 2 * e)     * 64 + j],
                                          aw1[(size_t)(k0 + 2 * e + 1) * 64 + j]);
            }
        }
    }
    float a2[4];
    #pragma unroll
    for (int nb = 0; nb < 4; ++nb) a2[nb] = aw2[nb * 16 + c];
    float b2s = ab2[0];

    for (int pass = 0; pass < 4; ++pass) {
        long r0 = (long)blk * 256 + pass * 64 + wid * 16;
        if (r0 >= n) break;                    // wave-coherent skip
        long myrow = r0 + c;
        if (myrow >= n) myrow = n - 1;
        const float4* Xr = (const float4*)(X + (size_t)myrow * DIM);

        // A fragments: 8 consecutive k per lane, 4 K-steps
        ABu af[4];
        #pragma unroll
        for (int kb = 0; kb < 4; ++kb) {
            float4 a = Xr[kb * 8 + kg * 2];
            float4 b = Xr[kb * 8 + kg * 2 + 1];
            af[kb].u[0] = pack2bf(a.x, a.y);
            af[kb].u[1] = pack2bf(a.z, a.w);
            af[kb].u[2] = pack2bf(b.x, b.y);
            af[kb].u[3] = pack2bf(b.z, b.w);
        }

        f32x4 acc[4];
        #pragma unroll
        for (int nb = 0; nb < 4; ++nb) { acc[nb].x = 0.f; acc[nb].y = 0.f; acc[nb].z = 0.f; acc[nb].w = 0.f; }
        #pragma unroll
        for (int kb = 0; kb < 4; ++kb) {
            #pragma unroll
            for (int nb = 0; nb < 4; ++nb) {
                acc[nb] = __builtin_amdgcn_mfma_f32_16x16x32_bf16(af[kb].v, wf[kb][nb].v, acc[nb], 0, 0, 0);
            }
        }

        // epilogue: this lane holds rows rgrp..rgrp+3 at col j = nb*16 + c
        int rgrp = kg * 4;
        float part[4] = {0.f, 0.f, 0.f, 0.f};
        #pragma unroll
        for (int reg = 0; reg < 4; ++reg) {
            long rr = r0 + rgrp + reg;
            bool v = rr < n;
            int h = v ? idx[rr] : 0;
            const float* mp = mpart + (size_t)h * 64;
            #pragma unroll
            for (int nb = 0; nb < 4; ++nb) {
                float hv = acc[nb][reg] + mp[nb * 16 + c];
                hv = hv > 0.f ? hv : 0.2f * hv;
                part[reg] += hv * a2[nb];
            }
        }
        #pragma unroll
        for (int reg = 0; reg < 4; ++reg) {
            float p = part[reg];
            p += __shfl_xor(p, 1, 64);
            p += __shfl_xor(p, 2, 64);
            p += __shfl_xor(p, 4, 64);
            p += __shfl_xor(p, 8, 64);
            part[reg] = p;
        }
        if (c == 0) {
            #pragma unroll
            for (int reg = 0; reg < 4; ++reg) {
                long rr = r0 + rgrp + reg;
                if (rr < n) scores[rr] = part[reg] + b2s;
            }
        }
    }
}

// ---------------- K4: per-herb softmax + weighted row sum, both sides -----
__global__ __launch_bounds__(64) void k_attn_both(
        const float* __restrict__ hA, const float* __restrict__ hB,
        const int* __restrict__ startA, const int* __restrict__ startB,
        const float* __restrict__ scoresA, const float* __restrict__ scoresB,
        float* __restrict__ outA, float* __restrict__ outB) {
    int bid = blockIdx.x;
    bool sideA = bid < H_HERBS;
    int h = sideA ? bid : bid - H_HERBS;
    const float* X = sideA ? hA : hB;
    const int* start = sideA ? startA : startB;
    const float* scores = sideA ? scoresA : scoresB;
    float* out = sideA ? outA : outB;

    int lane = threadIdx.x;
    int half = lane >> 5, li = lane & 31;
    int s = start[h], e = start[h + 1];
    const float4* X4 = (const float4*)X;
    float4 acc = make_float4(0.f, 0.f, 0.f, 0.f);
    if (e > s) {
        float mx = -INFINITY;
        for (int r = s + lane; r < e; r += 64) mx = fmaxf(mx, scores[r]);
        #pragma unroll
        for (int o = 32; o; o >>= 1) mx = fmaxf(mx, __shfl_xor(mx, o, 64));
        float sum = 0.f;
        for (int r = s + lane; r < e; r += 64) sum += __expf(scores[r] - mx);
        #pragma unroll
        for (int o = 32; o; o >>= 1) sum += __shfl_xor(sum, o, 64);
        float invden = 1.0f / (sum + 1e-16f);

        int r = s + half;
        for (; r + 2 < e; r += 4) {
            float w0 = __expf(scores[r] - mx) * invden;
            float w1 = __expf(scores[r + 2] - mx) * invden;
            float4 v0 = X4[(size_t)r * 32 + li];
            float4 v1 = X4[(size_t)(r + 2) * 32 + li];
            acc.x += w0 * v0.x + w1 * v1.x;
            acc.y += w0 * v0.y + w1 * v1.y;
            acc.z += w0 * v0.z + w1 * v1.z;
            acc.w += w0 * v0.w + w1 * v1.w;
        }
        if (r < e) {
            float w0 = __expf(scores[r] - mx) * invden;
            float4 v0 = X4[(size_t)r * 32 + li];
            acc.x += w0 * v0.x; acc.y += w0 * v0.y;
            acc.z += w0 * v0.z; acc.w += w0 * v0.w;
        }
    }
    acc.x += __shfl_xor(acc.x, 32, 64);
    acc.y += __shfl_xor(acc.y, 32, 64);
    acc.z += __shfl_xor(acc.z, 32, 64);
    acc.w += __shfl_xor(acc.w, 32, 64);
    if (half == 0) {
        ((float4*)out)[(size_t)h * 32 + li] = acc;
    }
}

// ---------------- K5: fusion MLP, register-tiled GEMM -----------------
#define HPB 16
__global__ __launch_bounds__(256) void k_fusion(
        const float* __restrict__ HA, const float* __restrict__ HB,
        const float* __restrict__ fw1, const float* __restrict__ fb1,
        const float* __restrict__ fw2, const float* __restrict__ fb2,
        float* __restrict__ out) {
    __shared__ float feat[HPB][512];
    __shared__ float hid[HPB][256];
    int t = threadIdx.x;
    int h0 = blockIdx.x * HPB;

    for (int idx = t; idx < HPB * DIM; idx += 256) {
        int hh = idx >> 7, c = idx & 127;
        int h = h0 + hh;
        float a = 0.f, b = 0.f;
        if (h < H_HERBS) { a = HA[(size_t)h * DIM + c]; b = HB[(size_t)h * DIM + c]; }
        feat[hh][c]       = a;
        feat[hh][128 + c] = b;
        feat[hh][256 + c] = a * b;
        feat[hh][384 + c] = fabsf(a - b);
    }
    __syncthreads();

    {
        int c = t & 63, g = t >> 6;
        float4 acc[4];
        #pragma unroll
        for (int m = 0; m < 4; ++m) acc[m] = make_float4(0.f, 0.f, 0.f, 0.f);
        const float4* W1 = (const float4*)fw1;
        for (int k = 0; k < 512; k += 4) {
            float4 w0 = W1[(size_t)(k + 0) * 64 + c];
            float4 w1 = W1[(size_t)(k + 1) * 64 + c];
            float4 w2 = W1[(size_t)(k + 2) * 64 + c];
            float4 w3 = W1[(size_t)(k + 3) * 64 + c];
            #pragma unroll
            for (int m = 0; m < 4; ++m) {
                float4 f = *(const float4*)&feat[4 * g + m][k];
                acc[m].x += f.x * w0.x + f.y * w1.x + f.z * w2.x + f.w * w3.x;
                acc[m].y += f.x * w0.y + f.y * w1.y + f.z * w2.y + f.w * w3.y;
                acc[m].z += f.x * w0.z + f.y * w1.z + f.z * w2.z + f.w * w3.z;
                acc[m].w += f.x * w0.w + f.y * w1.w + f.z * w2.w + f.w * w3.w;
            }
        }
        float4 b1v = ((const float4*)fb1)[c];
        #pragma unroll
        for (int m = 0; m < 4; ++m) {
            float4 hv;
            hv.x = fmaxf(acc[m].x + b1v.x, 0.f);
            hv.y = fmaxf(acc[m].y + b1v.y, 0.f);
            hv.z = fmaxf(acc[m].z + b1v.z, 0.f);
            hv.w = fmaxf(acc[m].w + b1v.w, 0.f);
            *(float4*)&hid[4 * g + m][4 * c] = hv;
        }
    }
    __syncthreads();

    {
        int c2 = t & 31, g2 = t >> 5;
        float4 acc[2];
        #pragma unroll
        for (int m = 0; m < 2; ++m) acc[m] = make_float4(0.f, 0.f, 0.f, 0.f);
        const float4* W2 = (const float4*)fw2;
        for (int k = 0; k < 256; k += 4) {
            float4 w0 = W2[(size_t)(k + 0) * 32 + c2];
            float4 w1 = W2[(size_t)(k + 1) * 32 + c2];
            float4 w2v = W2[(size_t)(k + 2) * 32 + c2];
            float4 w3 = W2[(size_t)(k + 3) * 32 + c2];
            #pragma unroll
            for (int m = 0; m < 2; ++m) {
                float4 hv = *(const float4*)&hid[2 * g2 + m][k];
                acc[m].x += hv.x * w0.x + hv.y * w1.x + hv.z * w2v.x + hv.w * w3.x;
                acc[m].y += hv.x * w0.y + hv.y * w1.y + hv.z * w2v.y + hv.w * w3.y;
                acc[m].z += hv.x * w0.z + hv.y * w1.z + hv.z * w2v.z + hv.w * w3.z;
                acc[m].w += hv.x * w0.w + hv.y * w1.w + hv.z * w2v.w + hv.w * w3.w;
            }
        }
        float4 b2v = ((const float4*)fb2)[c2];
        #pragma unroll
        for (int m = 0; m < 2; ++m) {
            int h = h0 + 2 * g2 + m;
            if (h < H_HERBS) {
                float4 o;
                o.x = acc[m].x + b2v.x; o.y = acc[m].y + b2v.y;
                o.z = acc[m].z + b2v.z; o.w = acc[m].w + b2v.w;
                ((float4*)out)[(size_t)h * 32 + c2] = o;
            }
        }
    }
}

extern "C" void kernel_launch(void* const* d_in, const int* in_sizes, int n_in,
                              void* d_out, int out_size, void* d_ws, size_t ws_size,
                              hipStream_t stream) {
    const float* hA  = (const float*)d_in[0];
    const float* hB  = (const float*)d_in[1];
    const int*   idxA = (const int*)d_in[2];
    const int*   idxB = (const int*)d_in[3];
    const float* aw1 = (const float*)d_in[5];
    const float* ab1 = (const float*)d_in[6];
    const float* aw2 = (const float*)d_in[7];
    const float* ab2 = (const float*)d_in[8];
    const float* fw1 = (const float*)d_in[9];
    const float* fb1 = (const float*)d_in[10];
    const float* fw2 = (const float*)d_in[11];
    const float* fb2 = (const float*)d_in[12];

    int nA = in_sizes[0] / DIM;
    int nB = in_sizes[1] / DIM;

    float* out  = (float*)d_out;
    float* outI = out;
    float* outA = out + (size_t)H_HERBS * DIM;
    float* outB = out + (size_t)2 * H_HERBS * DIM;

    char* w = (char*)d_ws;
    auto carve = [&](size_t bytes) { char* p = w; w += (bytes + 255) & ~(size_t)255; return p; };
    int*   startA  = (int*)carve((size_t)(H_HERBS + 1) * sizeof(int));
    int*   startB  = (int*)carve((size_t)(H_HERBS + 1) * sizeof(int));
    float* mpartA  = (float*)carve((size_t)H_HERBS * 64 * sizeof(float));
    float* mpartB  = (float*)carve((size_t)H_HERBS * 64 * sizeof(float));
    float* scoresA = (float*)carve((size_t)nA * sizeof(float));
    float* scoresB = (float*)carve((size_t)nB * sizeof(float));

    int gridA = (nA + 255) / 256;
    int gridB = (nB + 255) / 256;

    k_starts<<<(H_HERBS + 1 + 255) / 256, 256, 0, stream>>>(idxA, idxB, nA, nB, startA, startB);

    k_mean_both<<<2 * H_HERBS, 64, 0, stream>>>(hA, hB, startA, startB, aw1, ab1, mpartA, mpartB);

    k_scores_mfma<<<gridA + gridB, 256, 0, stream>>>(hA, idxA, mpartA, nA, gridA,
                                                     hB, idxB, mpartB, nB,
                                                     aw1, aw2, ab2, scoresA, scoresB);

    k_attn_both<<<2 * H_HERBS, 64, 0, stream>>>(hA, hB, startA, startB, scoresA, scoresB, outA, outB);

    k_fusion<<<(H_HERBS + HPB - 1) / HPB, 256, 0, stream>>>(outA, outB, fw1, fb1, fw2, fb2, outI);
}